// Round 6
// baseline (435.797 us; speedup 1.0000x reference)
//
#include <hip/hip_runtime.h>
#include <hip/hip_bf16.h>
#include <math.h>

#define BATCH 4096
#define NSIG  16384
#define MREF  12
#define KBIN  2048

constexpr float SIM_EPS = 1e-4f;
constexpr float TWO_PI = 6.2831853071795864769f;

typedef __attribute__((ext_vector_type(8))) short bfrag;   // 8 bf16 (4 VGPR)
typedef __attribute__((ext_vector_type(4))) float f32x4;
typedef __attribute__((ext_vector_type(4))) int   i32x4;
typedef __attribute__((ext_vector_type(4))) unsigned u32x4;

// Block-invariant twiddle tables, generated once per call by setup_kernel.
__device__ unsigned g_wtab[16 * 256 * 4];   // [(mt*4+ks)*2+ri][t] as uint4 (64 KB)
__device__ unsigned g_b2tab[1024 * 4];      // [((ch*2+s)*2+ri)*64+lane] as uint4 (16 KB)
__device__ unsigned g_utw[32 * 128 * 4];    // [a=k1>>2][n2] word q = pack(re,im) of e^{-2pi i (4a+q)n2/16384} (64 KB)
__device__ float    g_msn[MREF];

__device__ inline unsigned short f2bf(float x) {
  unsigned u = __builtin_bit_cast(unsigned, x);
  u += 0x7fffu + ((u >> 16) & 1u);      // round-to-nearest-even
  return (unsigned short)(u >> 16);
}
__device__ inline unsigned pkbf(float lo, float hi) {
  return (unsigned)f2bf(lo) | ((unsigned)f2bf(hi) << 16);   // low 16 = lo
}
__device__ inline float bflo(unsigned u) { return __builtin_bit_cast(float, u << 16); }
__device__ inline float bfhi(unsigned u) { return __builtin_bit_cast(float, u & 0xffff0000u); }
__device__ inline f32x4 mfma16(bfrag a, bfrag b, f32x4 c) {
  return __builtin_amdgcn_mfma_f32_16x16x32_bf16(a, b, c, 0, 0, 0);
}

// ---- setup: twiddle tables + msn, all parallel; grid = 37 blocks ----
__global__ __launch_bounds__(256) void setup_kernel(const float* __restrict__ ms) {
  const int blk = blockIdx.x, t = threadIdx.x;
  if (blk < 16) {
    // W fragments: slot = (mt*4+ks)*2+ri = blk
    const int ri = blk & 1, ks = (blk >> 1) & 3, mt = blk >> 3;
    const int lane = t & 63, w = t >> 6, c = lane & 15, g = lane >> 4;
    const int k1 = 32 * w + 16 * mt + c;
    unsigned wd[4];
    #pragma unroll
    for (int jp = 0; jp < 4; ++jp) {
      float v[2];
      #pragma unroll
      for (int h = 0; h < 2; ++h) {
        const int n1 = 32 * ks + 8 * g + 2 * jp + h;
        const float th = TWO_PI * (float)((k1 * n1) & 127) / 128.f;
        float sn, cs; sincosf(th, &sn, &cs);
        v[h] = ri ? -sn : cs;                      // Phi = (cos, -sin)
      }
      wd[jp] = pkbf(v[0], v[1]);
    }
    *(u32x4*)&g_wtab[(blk * 256 + t) * 4] = (u32x4){wd[0], wd[1], wd[2], wd[3]};
  } else if (blk == 16) {
    // B2 fragments: 1024 uint4, 4 per thread
    #pragma unroll
    for (int r = 0; r < 4; ++r) {
      const int e = t * 4 + r;
      const int lane = e & 63, ri = (e >> 6) & 1, s_ = (e >> 7) & 1, ch = (e >> 8) & 3;
      const int c = lane & 15, g = lane >> 4;
      unsigned wd[4];
      #pragma unroll
      for (int i = 0; i < 4; ++i) {
        const int ang = (c * (32 * ch + 16 * s_ + 4 * g + i)) & 127;
        const float th = TWO_PI * (float)ang / 128.f;
        float sn, cs; sincosf(th, &sn, &cs);
        // Phi=(cs,-sn): frag0 word = pack(Re,-Im) = (cs, sn); frag1 = pack(Im, Re) = (-sn, cs)
        wd[i] = ri ? pkbf(-sn, cs) : pkbf(cs, sn);
      }
      *(u32x4*)&g_b2tab[e * 4] = (u32x4){wd[0], wd[1], wd[2], wd[3]};
    }
  } else if (blk < 25) {
    // U twiddles: 4096 uint4 over 8 blocks
    const int base = (blk - 17) * 512 + t;
    #pragma unroll
    for (int r = 0; r < 2; ++r) {
      const int e = base + r * 256;        // = a*128 + n2
      const int a = e >> 7, n2 = e & 127;
      unsigned wd[4];
      #pragma unroll
      for (int q = 0; q < 4; ++q) {
        const int ang = ((4 * a + q) * n2) & 16383;
        const float th = TWO_PI * (float)ang / 16384.f;
        float sn, cs; sincosf(th, &sn, &cs);
        wd[q] = pkbf(cs, -sn);
      }
      *(u32x4*)&g_utw[e * 4] = (u32x4){wd[0], wd[1], wd[2], wd[3]};
    }
  } else {
    const int m = blk - 25;
    if (m < MREF) {
      float p = 0.f;
      for (int i = t; i < KBIN; i += 256) { float v = ms[m * KBIN + i]; p += v * v; }
      #pragma unroll
      for (int o = 32; o; o >>= 1) p += __shfl_xor(p, o, 64);
      __shared__ float r4[4];
      if ((t & 63) == 0) r4[t >> 6] = p;
      __syncthreads();
      if (t == 0) g_msn[m] = r4[0] + r4[1] + r4[2] + r4[3];
    }
  }
}

// ---- main: per-batch 2048-bin DFT via two-stage CT, both stages MFMA ----
__global__ __launch_bounds__(256, 2) void consonance_kernel(
    const float* __restrict__ Y, const float* __restrict__ ms,
    const float* __restrict__ diss, float* __restrict__ out) {
  __shared__ __align__(16) unsigned short Ysb[128 * 128]; // bf16 [n2][n1], 16B-block XOR swizzle
  __shared__ __align__(16) unsigned Ua[4 * 32 * 32];      // per-wave packed U (bf16 re|im), swizzled
  __shared__ float red[4][13];

  const int t = threadIdx.x;
  const int b = blockIdx.x;
  const int lane = t & 63;
  const int w = t >> 6;           // wave 0..3, owns k1 in [32w, 32w+32)
  const int g = lane >> 4;        // 0..3
  const int c = lane & 15;        // 0..15

  // ---- load Y row -> bf16 transposed swizzled LDS: Ysb[n2][n1] ----
  {
    const int c0 = (t & 31) << 2;         // n2 base (4 cols)
    const int h  = t >> 5;                // 0..7 -> n1 range [16h,16h+16)
    const float* yrow = Y + (size_t)b * NSIG + c0;
    float4 v[16];
    #pragma unroll
    for (int r = 0; r < 16; ++r)
      v[r] = *(const float4*)(yrow + 128 * (16 * h + r));
    #pragma unroll
    for (int u = 0; u < 2; ++u) {
      #pragma unroll
      for (int cc = 0; cc < 4; ++cc) {
        const int n2 = c0 + cc;
        unsigned p0 = pkbf((&v[8*u+0].x)[cc], (&v[8*u+1].x)[cc]);
        unsigned p1 = pkbf((&v[8*u+2].x)[cc], (&v[8*u+3].x)[cc]);
        unsigned p2 = pkbf((&v[8*u+4].x)[cc], (&v[8*u+5].x)[cc]);
        unsigned p3 = pkbf((&v[8*u+6].x)[cc], (&v[8*u+7].x)[cc]);
        const int blk = (2 * h + u) ^ (n2 & 7);
        *(i32x4*)((char*)Ysb + n2 * 256 + (blk << 4)) =
            (i32x4){(int)p0, (int)p1, (int)p2, (int)p3};
      }
    }
  }

  // ---- W fragments from table (coalesced dwordx4, L2-hot) ----
  bfrag Wr[2][4], Wi[2][4];
  #pragma unroll
  for (int mt = 0; mt < 2; ++mt)
    #pragma unroll
    for (int ks = 0; ks < 4; ++ks) {
      Wr[mt][ks] = *(const bfrag*)&g_wtab[(((mt * 4 + ks) * 2 + 0) * 256 + t) * 4];
      Wi[mt][ks] = *(const bfrag*)&g_wtab[(((mt * 4 + ks) * 2 + 1) * 256 + t) * 4];
    }

  f32x4 aXr[2] = {{0.f,0.f,0.f,0.f},{0.f,0.f,0.f,0.f}};
  f32x4 aXi[2] = {{0.f,0.f,0.f,0.f},{0.f,0.f,0.f,0.f}};
  unsigned* uw = Ua + (w << 10);  // 1024 words per wave

  __syncthreads();   // Ysb ready

  #pragma unroll 1
  for (int ch = 0; ch < 4; ++ch) {
    // ---- stage-1 B-frags from Ysb ----
    bfrag bfr[2][4];
    #pragma unroll
    for (int nt = 0; nt < 2; ++nt) {
      const int n2 = 32 * ch + 16 * nt + c;
      #pragma unroll
      for (int ks = 0; ks < 4; ++ks) {
        const int blk = (4 * ks + g) ^ (n2 & 7);
        bfr[nt][ks] = *(const bfrag*)((const char*)Ysb + n2 * 256 + (blk << 4));
      }
    }
    // ---- stage-1 MFMA ----
    f32x4 aTr[2][2] = {{{0.f,0.f,0.f,0.f},{0.f,0.f,0.f,0.f}},
                       {{0.f,0.f,0.f,0.f},{0.f,0.f,0.f,0.f}}};
    f32x4 aTi[2][2] = {{{0.f,0.f,0.f,0.f},{0.f,0.f,0.f,0.f}},
                       {{0.f,0.f,0.f,0.f},{0.f,0.f,0.f,0.f}}};
    #pragma unroll
    for (int mt = 0; mt < 2; ++mt)
      #pragma unroll
      for (int nt = 0; nt < 2; ++nt)
        #pragma unroll
        for (int ks = 0; ks < 4; ++ks) {
          aTr[mt][nt] = mfma16(Wr[mt][ks], bfr[nt][ks], aTr[mt][nt]);
          aTi[mt][nt] = mfma16(Wi[mt][ks], bfr[nt][ks], aTi[mt][nt]);
        }
    // ---- U = T * Utw (table), pack bf16, write per-wave LDS ----
    #pragma unroll
    for (int nt = 0; nt < 2; ++nt) {
      const int n2 = 32 * ch + 16 * nt + c;
      #pragma unroll
      for (int mt = 0; mt < 2; ++mt) {
        const int a = 8 * w + 4 * mt + g;            // (32w+16mt+4g)>>2
        const u32x4 tw = *(const u32x4*)&g_utw[(a * 128 + n2) * 4];
        #pragma unroll
        for (int q = 0; q < 4; ++q) {
          const float twr = bflo(tw[q]), twi = bfhi(tw[q]);
          const float tr = aTr[mt][nt][q], ti = aTi[mt][nt][q];
          const float ur = tr * twr - ti * twi;
          const float ui = tr * twi + ti * twr;
          const int rl = 16 * mt + 4 * g + q;
          const int tt = 16 * nt + c;
          uw[rl * 32 + (tt ^ ((rl & 7) << 2))] = pkbf(ur, ui);
        }
      }
    }
    // ---- stage-2 B-frags from table ----
    bfrag B2[2][2];
    #pragma unroll
    for (int s = 0; s < 2; ++s) {
      B2[0][s] = *(const bfrag*)&g_b2tab[(((ch * 2 + s) * 2 + 0) * 64 + lane) * 4];
      B2[1][s] = *(const bfrag*)&g_b2tab[(((ch * 2 + s) * 2 + 1) * 64 + lane) * 4];
    }
    // ---- stage-2 MFMA: A from own-wave LDS (no barrier needed) ----
    #pragma unroll
    for (int mt = 0; mt < 2; ++mt) {
      const int rl = 16 * mt + c;
      #pragma unroll
      for (int s = 0; s < 2; ++s) {
        const int t4 = (16 * s + 4 * g) ^ ((rl & 7) << 2);
        bfrag af = *(const bfrag*)((const char*)uw + rl * 128 + (t4 << 2));
        aXr[mt] = mfma16(af, B2[0][s], aXr[mt]);
        aXi[mt] = mfma16(af, B2[1][s], aXi[mt]);
      }
    }
  }

  // ---- magnitude + fused similarity reduction ----
  // lane holds X(k1 = 32w+16mt+4g+q, k2 = c) -> k = k1 + 128*k2; q-contiguous -> float4 ms loads
  const float scale = 2.0f / (float)NSIG;
  float yfv[2][4], S = 0.f;
  #pragma unroll
  for (int mt = 0; mt < 2; ++mt)
    #pragma unroll
    for (int q = 0; q < 4; ++q) {
      const float xr = aXr[mt][q], xi = aXi[mt][q];
      const float yf = scale * sqrtf(xr * xr + xi * xi);
      yfv[mt][q] = yf;
      S += yf * yf;
    }
  float dot[MREF];
  #pragma unroll
  for (int m = 0; m < MREF; ++m) dot[m] = 0.f;
  const int kb0 = 32 * w + 4 * g + 128 * c;
  #pragma unroll
  for (int m = 0; m < MREF; ++m) {
    #pragma unroll
    for (int mt = 0; mt < 2; ++mt) {
      const float4 mv = *(const float4*)&ms[m * KBIN + kb0 + 16 * mt];
      dot[m] = fmaf(yfv[mt][0], mv.x, dot[m]);
      dot[m] = fmaf(yfv[mt][1], mv.y, dot[m]);
      dot[m] = fmaf(yfv[mt][2], mv.z, dot[m]);
      dot[m] = fmaf(yfv[mt][3], mv.w, dot[m]);
    }
  }
  #pragma unroll
  for (int o = 32; o; o >>= 1) {
    S += __shfl_xor(S, o, 64);
    #pragma unroll
    for (int m = 0; m < MREF; ++m) dot[m] += __shfl_xor(dot[m], o, 64);
  }
  if (lane == 0) {
    red[w][0] = S;
    #pragma unroll
    for (int m = 0; m < MREF; ++m) red[w][1 + m] = dot[m];
  }
  __syncthreads();
  if (t == 0) {
    const float St = red[0][0] + red[1][0] + red[2][0] + red[3][0];
    float ssum = 0.f, wsum = 0.f;
    for (int m = 0; m < MREF; ++m) {
      const float dm = red[0][1 + m] + red[1][1 + m] + red[2][1 + m] + red[3][1 + m];
      const float d2 = St + g_msn[m] - 2.f * dm;
      const float dist = sqrtf(fmaxf(d2, 0.f));
      const float sim = 1.f / (dist + SIM_EPS);
      ssum += sim;
      wsum += sim * (1.f - diss[m]);
    }
    out[b] = wsum / ssum;
  }
}

extern "C" void kernel_launch(void* const* d_in, const int* in_sizes, int n_in,
                              void* d_out, int out_size, void* d_ws, size_t ws_size,
                              hipStream_t stream) {
  const float* Y    = (const float*)d_in[0];
  const float* ms   = (const float*)d_in[1];
  const float* diss = (const float*)d_in[2];
  float* outp = (float*)d_out;
  setup_kernel<<<37, 256, 0, stream>>>(ms);
  consonance_kernel<<<BATCH, 256, 0, stream>>>(Y, ms, diss, outp);
}

// Round 7
// 420.520 us; speedup vs baseline: 1.0363x; 1.0363x over previous
//
#include <hip/hip_runtime.h>
#include <hip/hip_bf16.h>
#include <math.h>

#define BATCH 4096
#define NSIG  16384
#define MREF  12
#define KBIN  2048

constexpr float SIM_EPS = 1e-4f;
constexpr float TWO_PI = 6.2831853071795864769f;

typedef __attribute__((ext_vector_type(8))) short bfrag;   // 8 bf16 (4 VGPR)
typedef __attribute__((ext_vector_type(4))) float f32x4;
typedef __attribute__((ext_vector_type(4))) int   i32x4;
typedef __attribute__((ext_vector_type(4))) unsigned u32x4;

// Block-invariant twiddle tables, generated once per call by setup_kernel.
__device__ unsigned g_wtab[16 * 256 * 4];   // [(mt*4+ks)*2+ri][t] as uint4 (64 KB)
__device__ unsigned g_b2tab[1024 * 4];      // [((ch*2+s)*2+ri)*64+lane] as uint4 (16 KB)
__device__ unsigned g_utw[32 * 128 * 4];    // [a=k1>>2][n2] word q = pack(re,im) of e^{-2pi i (4a+q)n2/16384} (64 KB)
__device__ float    g_msn[MREF];

// single-instruction pack: dst.lo = bf16(lo), dst.hi = bf16(hi)   [T12 verified form]
__device__ inline unsigned pkbf(float lo, float hi) {
  unsigned r;
  asm("v_cvt_pk_bf16_f32 %0, %1, %2" : "=v"(r) : "v"(lo), "v"(hi));
  return r;
}
__device__ inline float bflo(unsigned u) { return __builtin_bit_cast(float, u << 16); }
__device__ inline float bfhi(unsigned u) { return __builtin_bit_cast(float, u & 0xffff0000u); }
__device__ inline f32x4 mfma16(bfrag a, bfrag b, f32x4 c) {
  return __builtin_amdgcn_mfma_f32_16x16x32_bf16(a, b, c, 0, 0, 0);
}
// balanced LDS swizzle for Ysb (write AND read conflict-free, verified by bank count)
__device__ inline int fsw(int n2) { return (n2 ^ (n2 >> 2)) & 7; }

// ---- setup: twiddle tables + msn, all parallel; grid = 37 blocks ----
__global__ __launch_bounds__(256) void setup_kernel(const float* __restrict__ ms) {
  const int blk = blockIdx.x, t = threadIdx.x;
  if (blk < 16) {
    const int ri = blk & 1, ks = (blk >> 1) & 3, mt = blk >> 3;
    const int lane = t & 63, w = t >> 6, c = lane & 15, g = lane >> 4;
    const int k1 = 32 * w + 16 * mt + c;
    unsigned wd[4];
    #pragma unroll
    for (int jp = 0; jp < 4; ++jp) {
      float v[2];
      #pragma unroll
      for (int h = 0; h < 2; ++h) {
        const int n1 = 32 * ks + 8 * g + 2 * jp + h;
        const float th = TWO_PI * (float)((k1 * n1) & 127) / 128.f;
        float sn, cs; sincosf(th, &sn, &cs);
        v[h] = ri ? -sn : cs;                      // Phi = (cos, -sin)
      }
      wd[jp] = pkbf(v[0], v[1]);
    }
    *(u32x4*)&g_wtab[(blk * 256 + t) * 4] = (u32x4){wd[0], wd[1], wd[2], wd[3]};
  } else if (blk == 16) {
    #pragma unroll
    for (int r = 0; r < 4; ++r) {
      const int e = t * 4 + r;
      const int lane = e & 63, ri = (e >> 6) & 1, s_ = (e >> 7) & 1, ch = (e >> 8) & 3;
      const int c = lane & 15, g = lane >> 4;
      unsigned wd[4];
      #pragma unroll
      for (int i = 0; i < 4; ++i) {
        const int ang = (c * (32 * ch + 16 * s_ + 4 * g + i)) & 127;
        const float th = TWO_PI * (float)ang / 128.f;
        float sn, cs; sincosf(th, &sn, &cs);
        wd[i] = ri ? pkbf(-sn, cs) : pkbf(cs, sn);
      }
      *(u32x4*)&g_b2tab[e * 4] = (u32x4){wd[0], wd[1], wd[2], wd[3]};
    }
  } else if (blk < 25) {
    const int base = (blk - 17) * 512 + t;
    #pragma unroll
    for (int r = 0; r < 2; ++r) {
      const int e = base + r * 256;        // = a*128 + n2
      const int a = e >> 7, n2 = e & 127;
      unsigned wd[4];
      #pragma unroll
      for (int q = 0; q < 4; ++q) {
        const int ang = ((4 * a + q) * n2) & 16383;
        const float th = TWO_PI * (float)ang / 16384.f;
        float sn, cs; sincosf(th, &sn, &cs);
        wd[q] = pkbf(cs, -sn);
      }
      *(u32x4*)&g_utw[e * 4] = (u32x4){wd[0], wd[1], wd[2], wd[3]};
    }
  } else {
    const int m = blk - 25;
    if (m < MREF) {
      float p = 0.f;
      for (int i = t; i < KBIN; i += 256) { float v = ms[m * KBIN + i]; p += v * v; }
      #pragma unroll
      for (int o = 32; o; o >>= 1) p += __shfl_xor(p, o, 64);
      __shared__ float r4[4];
      if ((t & 63) == 0) r4[t >> 6] = p;
      __syncthreads();
      if (t == 0) g_msn[m] = r4[0] + r4[1] + r4[2] + r4[3];
    }
  }
}

// ---- main: per-batch 2048-bin DFT via two-stage CT, both stages MFMA ----
__global__ __launch_bounds__(256, 4) void consonance_kernel(
    const float* __restrict__ Y, const float* __restrict__ ms,
    const float* __restrict__ diss, float* __restrict__ out) {
  __shared__ __align__(16) unsigned short Ysb[128 * 128]; // bf16 [n2][n1], balanced XOR swizzle
  __shared__ __align__(16) unsigned Ua[4 * 32 * 32];      // per-wave packed U (bf16 re|im), swizzled
  __shared__ float red[4][13];

  const int t = threadIdx.x;
  const int b = blockIdx.x;
  const int lane = t & 63;
  const int w = t >> 6;           // wave 0..3, owns k1 in [32w, 32w+32)
  const int g = lane >> 4;        // 0..3
  const int c = lane & 15;        // 0..15

  // ---- W fragments from table (issued first; overlap with Y load) ----
  bfrag Wr[2][4], Wi[2][4];
  #pragma unroll
  for (int mt = 0; mt < 2; ++mt)
    #pragma unroll
    for (int ks = 0; ks < 4; ++ks) {
      Wr[mt][ks] = *(const bfrag*)&g_wtab[(((mt * 4 + ks) * 2 + 0) * 256 + t) * 4];
      Wi[mt][ks] = *(const bfrag*)&g_wtab[(((mt * 4 + ks) * 2 + 1) * 256 + t) * 4];
    }
  // ---- utw prefetch for chunk 0 (hidden under Y-load + barrier) ----
  u32x4 utwP[2][2];
  #pragma unroll
  for (int nt = 0; nt < 2; ++nt)
    #pragma unroll
    for (int mt = 0; mt < 2; ++mt) {
      const int a = 8 * w + 4 * mt + g;
      utwP[nt][mt] = *(const u32x4*)&g_utw[(a * 128 + (16 * nt + c)) * 4];
    }

  // ---- load Y row -> bf16 transposed swizzled LDS: Ysb[n2][n1], two halves ----
  {
    const int c0 = (t & 31) << 2;         // n2 base (4 cols)
    const int h  = t >> 5;                // 0..7 -> n1 range [16h,16h+16)
    const float* yrow = Y + (size_t)b * NSIG + c0;
    #pragma unroll
    for (int u = 0; u < 2; ++u) {
      float4 v[8];
      #pragma unroll
      for (int r = 0; r < 8; ++r)
        v[r] = *(const float4*)(yrow + 128 * (16 * h + 8 * u + r));
      #pragma unroll
      for (int cc = 0; cc < 4; ++cc) {
        const int n2 = c0 + cc;
        unsigned p0 = pkbf((&v[0].x)[cc], (&v[1].x)[cc]);
        unsigned p1 = pkbf((&v[2].x)[cc], (&v[3].x)[cc]);
        unsigned p2 = pkbf((&v[4].x)[cc], (&v[5].x)[cc]);
        unsigned p3 = pkbf((&v[6].x)[cc], (&v[7].x)[cc]);
        const int blk = (2 * h + u) ^ fsw(n2);
        *(i32x4*)((char*)Ysb + n2 * 256 + (blk << 4)) =
            (i32x4){(int)p0, (int)p1, (int)p2, (int)p3};
      }
    }
  }

  f32x4 aXr[2] = {{0.f,0.f,0.f,0.f},{0.f,0.f,0.f,0.f}};
  f32x4 aXi[2] = {{0.f,0.f,0.f,0.f},{0.f,0.f,0.f,0.f}};
  unsigned* uw = Ua + (w << 10);  // 1024 words per wave

  __syncthreads();   // Ysb ready

  #pragma unroll
  for (int ch = 0; ch < 4; ++ch) {
    // ---- issue B2 loads for THIS chunk (used ~600cy later in stage-2) ----
    bfrag B2[2][2];
    #pragma unroll
    for (int s = 0; s < 2; ++s) {
      B2[0][s] = *(const bfrag*)&g_b2tab[(((ch * 2 + s) * 2 + 0) * 64 + lane) * 4];
      B2[1][s] = *(const bfrag*)&g_b2tab[(((ch * 2 + s) * 2 + 1) * 64 + lane) * 4];
    }
    // ---- consume prefetched utw; issue prefetch for NEXT chunk ----
    u32x4 utwC[2][2];
    #pragma unroll
    for (int nt = 0; nt < 2; ++nt)
      #pragma unroll
      for (int mt = 0; mt < 2; ++mt) utwC[nt][mt] = utwP[nt][mt];
    if (ch < 3) {
      #pragma unroll
      for (int nt = 0; nt < 2; ++nt)
        #pragma unroll
        for (int mt = 0; mt < 2; ++mt) {
          const int a = 8 * w + 4 * mt + g;
          utwP[nt][mt] = *(const u32x4*)&g_utw[(a * 128 + (32 * (ch + 1) + 16 * nt + c)) * 4];
        }
    }
    // ---- stage-1 B-frags from Ysb ----
    bfrag bfr[2][4];
    #pragma unroll
    for (int nt = 0; nt < 2; ++nt) {
      const int n2 = 32 * ch + 16 * nt + c;
      #pragma unroll
      for (int ks = 0; ks < 4; ++ks) {
        const int blk = (4 * ks + g) ^ fsw(n2);
        bfr[nt][ks] = *(const bfrag*)((const char*)Ysb + n2 * 256 + (blk << 4));
      }
    }
    // ---- stage-1 MFMA ----
    f32x4 aTr[2][2] = {{{0.f,0.f,0.f,0.f},{0.f,0.f,0.f,0.f}},
                       {{0.f,0.f,0.f,0.f},{0.f,0.f,0.f,0.f}}};
    f32x4 aTi[2][2] = {{{0.f,0.f,0.f,0.f},{0.f,0.f,0.f,0.f}},
                       {{0.f,0.f,0.f,0.f},{0.f,0.f,0.f,0.f}}};
    #pragma unroll
    for (int mt = 0; mt < 2; ++mt)
      #pragma unroll
      for (int nt = 0; nt < 2; ++nt)
        #pragma unroll
        for (int ks = 0; ks < 4; ++ks) {
          aTr[mt][nt] = mfma16(Wr[mt][ks], bfr[nt][ks], aTr[mt][nt]);
          aTi[mt][nt] = mfma16(Wi[mt][ks], bfr[nt][ks], aTi[mt][nt]);
        }
    // ---- U = T * Utw (prefetched), pack bf16, write per-wave LDS ----
    #pragma unroll
    for (int nt = 0; nt < 2; ++nt) {
      #pragma unroll
      for (int mt = 0; mt < 2; ++mt) {
        const u32x4 tw = utwC[nt][mt];
        #pragma unroll
        for (int q = 0; q < 4; ++q) {
          const float twr = bflo(tw[q]), twi = bfhi(tw[q]);
          const float tr = aTr[mt][nt][q], ti = aTi[mt][nt][q];
          const float ur = tr * twr - ti * twi;
          const float ui = tr * twi + ti * twr;
          const int rl = 16 * mt + 4 * g + q;
          const int tt = 16 * nt + c;
          uw[rl * 32 + (tt ^ ((rl & 7) << 2))] = pkbf(ur, ui);
        }
      }
    }
    // ---- stage-2 MFMA: A from own-wave LDS (no barrier needed) ----
    #pragma unroll
    for (int mt = 0; mt < 2; ++mt) {
      const int rl = 16 * mt + c;
      #pragma unroll
      for (int s = 0; s < 2; ++s) {
        const int t4 = (16 * s + 4 * g) ^ ((rl & 7) << 2);
        bfrag af = *(const bfrag*)((const char*)uw + rl * 128 + (t4 << 2));
        aXr[mt] = mfma16(af, B2[0][s], aXr[mt]);
        aXi[mt] = mfma16(af, B2[1][s], aXi[mt]);
      }
    }
  }

  // ---- magnitude + fused similarity reduction ----
  // lane holds X(k1 = 32w+16mt+4g+q, k2 = c) -> k = k1 + 128*k2; q-contiguous -> float4 ms loads
  const float scale = 2.0f / (float)NSIG;
  float yfv[2][4], S = 0.f;
  #pragma unroll
  for (int mt = 0; mt < 2; ++mt)
    #pragma unroll
    for (int q = 0; q < 4; ++q) {
      const float xr = aXr[mt][q], xi = aXi[mt][q];
      const float yf = scale * sqrtf(xr * xr + xi * xi);
      yfv[mt][q] = yf;
      S += yf * yf;
    }
  float dot[MREF];
  #pragma unroll
  for (int m = 0; m < MREF; ++m) dot[m] = 0.f;
  const int kb0 = 32 * w + 4 * g + 128 * c;
  #pragma unroll
  for (int m = 0; m < MREF; ++m) {
    #pragma unroll
    for (int mt = 0; mt < 2; ++mt) {
      const float4 mv = *(const float4*)&ms[m * KBIN + kb0 + 16 * mt];
      dot[m] = fmaf(yfv[mt][0], mv.x, dot[m]);
      dot[m] = fmaf(yfv[mt][1], mv.y, dot[m]);
      dot[m] = fmaf(yfv[mt][2], mv.z, dot[m]);
      dot[m] = fmaf(yfv[mt][3], mv.w, dot[m]);
    }
  }
  #pragma unroll
  for (int o = 32; o; o >>= 1) {
    S += __shfl_xor(S, o, 64);
    #pragma unroll
    for (int m = 0; m < MREF; ++m) dot[m] += __shfl_xor(dot[m], o, 64);
  }
  if (lane == 0) {
    red[w][0] = S;
    #pragma unroll
    for (int m = 0; m < MREF; ++m) red[w][1 + m] = dot[m];
  }
  __syncthreads();
  if (t == 0) {
    const float St = red[0][0] + red[1][0] + red[2][0] + red[3][0];
    float ssum = 0.f, wsum = 0.f;
    for (int m = 0; m < MREF; ++m) {
      const float dm = red[0][1 + m] + red[1][1 + m] + red[2][1 + m] + red[3][1 + m];
      const float d2 = St + g_msn[m] - 2.f * dm;
      const float dist = sqrtf(fmaxf(d2, 0.f));
      const float sim = 1.f / (dist + SIM_EPS);
      ssum += sim;
      wsum += sim * (1.f - diss[m]);
    }
    out[b] = wsum / ssum;
  }
}

extern "C" void kernel_launch(void* const* d_in, const int* in_sizes, int n_in,
                              void* d_out, int out_size, void* d_ws, size_t ws_size,
                              hipStream_t stream) {
  const float* Y    = (const float*)d_in[0];
  const float* ms   = (const float*)d_in[1];
  const float* diss = (const float*)d_in[2];
  float* outp = (float*)d_out;
  setup_kernel<<<37, 256, 0, stream>>>(ms);
  consonance_kernel<<<BATCH, 256, 0, stream>>>(Y, ms, diss, outp);
}